// Round 8
// baseline (227.739 us; speedup 1.0000x reference)
//
#include <hip/hip_runtime.h>
#include <hip/hip_bf16.h>
#include <cstddef>

#define D 128
#define SHIFT 10          // coarse bucket = 1024 nodes
#define RN (1 << SHIFT)
#define CAPLOG 15         // per-bucket pairs capacity 32768 (avg 16384, +>100 sigma)
#define CAP (1 << CAPLOG)

typedef __attribute__((ext_vector_type(8))) short bf16x8;
typedef __attribute__((ext_vector_type(16))) float f32x16;

static __device__ __forceinline__ unsigned short f2bf(float f) {
  return __builtin_bit_cast(unsigned short, __float2bfloat16(f));
}

__global__ void k_initcur(int* __restrict__ gcursor, int nc) {
  int c = blockIdx.x * blockDim.x + threadIdx.x;
  if (c < nc) gcursor[c] = c << CAPLOG;
}

// fused: per-node degree count + block-local counting sort into coarse buckets.
// One atomicAdd per (block,bucket) claims a contiguous run; the run is written
// by THIS block (one XCD) -> full-line write-back. pairs packed 4B:
// src (22 bits) | local-dst (10 bits) << 22.
__global__ __launch_bounds__(256) void k_psort(
    const int* __restrict__ src, const int* __restrict__ dst,
    int* __restrict__ cnt, int* __restrict__ gcursor,
    unsigned* __restrict__ pairs, int e, int nc) {
  __shared__ int hist[128];
  __shared__ int gbase[128];
  __shared__ int lcur[128];
  const int tid = threadIdx.x;
  const int base = blockIdx.x * 4096;
  const int m = min(4096, e - base);
  if (tid < 128) hist[tid] = 0;
  __syncthreads();
  int myd[16], mys[16];
#pragma unroll
  for (int j = 0; j < 16; ++j) {
    const int i = tid + j * 256;
    if (i < m) {
      myd[j] = dst[base + i];
      mys[j] = src[base + i];
      atomicAdd(&hist[myd[j] >> SHIFT], 1);
      atomicAdd(&cnt[myd[j]], 1);  // fused degree count
    }
  }
  __syncthreads();
  if (tid < nc) {
    gbase[tid] = atomicAdd(&gcursor[tid], hist[tid]);
    lcur[tid] = 0;
  }
  __syncthreads();
#pragma unroll
  for (int j = 0; j < 16; ++j) {
    const int i = tid + j * 256;
    if (i < m) {
      const int c = myd[j] >> SHIFT;
      const int off = atomicAdd(&lcur[c], 1);
      const unsigned pk = (unsigned)mys[j] | ((unsigned)(myd[j] & (RN - 1)) << 22);
      __builtin_nontemporal_store(pk, &pairs[gbase[c] + off]);
    }
  }
}

// exclusive scan of cnt (1024/block) -> rowptr + block sums; fused dinv
__global__ __launch_bounds__(256) void k_scan1(const int* __restrict__ cnt,
                                               int* __restrict__ rowptr,
                                               int* __restrict__ bsums,
                                               float* __restrict__ dinv, int n) {
  __shared__ int sdata[256];
  const int tid = threadIdx.x;
  const int idx = blockIdx.x * 1024 + tid * 4;
  int v[4], s = 0;
#pragma unroll
  for (int u = 0; u < 4; ++u) {
    int c = 0;
    if (idx + u < n) {
      c = cnt[idx + u];
      dinv[idx + u] = fminf(rsqrtf((float)(c + 1)), 1.0e6f);
    }
    v[u] = s; s += c;
  }
  sdata[tid] = s;
  __syncthreads();
  for (int off = 1; off < 256; off <<= 1) {
    int t = (tid >= off) ? sdata[tid - off] : 0;
    __syncthreads();
    sdata[tid] += t;
    __syncthreads();
  }
  const int excl = (tid > 0) ? sdata[tid - 1] : 0;
#pragma unroll
  for (int u = 0; u < 4; ++u)
    if (idx + u < n) rowptr[idx + u] = excl + v[u];
  if (tid == 255) bsums[blockIdx.x] = sdata[255];
}

__global__ __launch_bounds__(256) void k_scan2(int* __restrict__ bsums, int nb) {
  __shared__ int sdata[256];
  const int tid = threadIdx.x;
  sdata[tid] = (tid < nb) ? bsums[tid] : 0;
  __syncthreads();
  for (int off = 1; off < 256; off <<= 1) {
    int t = (tid >= off) ? sdata[tid - off] : 0;
    __syncthreads();
    sdata[tid] += t;
    __syncthreads();
  }
  const int excl = (tid > 0) ? sdata[tid - 1] : 0;
  if (tid < nb) bsums[tid] = excl;
}

__global__ void k_scan3(int* __restrict__ rowptr, const int* __restrict__ bsums, int n) {
  int i = blockIdx.x * blockDim.x + threadIdx.x;
  if (i < n) rowptr[i] += bsums[i >> 10];
}

// one block per coarse bucket: exact per-node scatter via LDS cursors; writes
// land in this bucket's contiguous srcs region (block-local, L2-dense).
__global__ __launch_bounds__(1024) void k_fine(
    const unsigned* __restrict__ pairs, const int* __restrict__ gcursor,
    const int* __restrict__ rowptr, int* __restrict__ srcs, int n) {
  __shared__ int rowLDS[RN];
  __shared__ int lcur[RN];
  const int c = blockIdx.x;
  const int node0 = c << SHIFT;
  const int nodes = min(RN, n - node0);
  const int tid = threadIdx.x;
  for (int v = tid; v < nodes; v += 1024) {
    rowLDS[v] = rowptr[node0 + v];
    lcur[v] = 0;
  }
  __syncthreads();
  const int beg = c << CAPLOG;
  const int end = gcursor[c];  // = c*CAP + bucket edge count
  for (int i = beg + tid; i < end; i += 1024) {
    const unsigned p = __builtin_nontemporal_load(&pairs[i]);
    const int lv = (int)(p >> 22);
    const int off = atomicAdd(&lcur[lv], 1);
    srcs[rowLDS[lv] + off] = (int)(p & 0x3FFFFFu);
  }
}

// g(bf16) = (x @ W^T + b) * dinv[r] via mfma_f32_32x32x16_bf16
__global__ __launch_bounds__(256) void k_gemm(
    const float* __restrict__ x, const float* __restrict__ W,
    const float* __restrict__ bias, const float* __restrict__ dinv,
    __hip_bfloat16* __restrict__ g, int n) {
  __shared__ unsigned short xs[128 * 128];
  __shared__ unsigned short Ws[128 * 128];
  const int tid = threadIdx.x;
  const int row0 = blockIdx.x * 128;

#pragma unroll
  for (int u = 0; u < 8; ++u) {
    const int f = tid + 256 * u;
    const int row = f >> 4;
    const int c = f & 15;
    const int ch = (c ^ (row & 7)) << 3;
    {
      const float4* p = reinterpret_cast<const float4*>(&W[(size_t)row * D + c * 8]);
      const float4 v0 = p[0], v1 = p[1];
      uint4 pk;
      pk.x = f2bf(v0.x) | ((unsigned)f2bf(v0.y) << 16);
      pk.y = f2bf(v0.z) | ((unsigned)f2bf(v0.w) << 16);
      pk.z = f2bf(v1.x) | ((unsigned)f2bf(v1.y) << 16);
      pk.w = f2bf(v1.z) | ((unsigned)f2bf(v1.w) << 16);
      *reinterpret_cast<uint4*>(&Ws[row * 128 + ch]) = pk;
    }
    {
      float4 v0 = make_float4(0.f, 0.f, 0.f, 0.f), v1 = v0;
      if (row0 + row < n) {
        const float4* p =
            reinterpret_cast<const float4*>(&x[(size_t)(row0 + row) * D + c * 8]);
        v0 = p[0]; v1 = p[1];
      }
      uint4 pk;
      pk.x = f2bf(v0.x) | ((unsigned)f2bf(v0.y) << 16);
      pk.y = f2bf(v0.z) | ((unsigned)f2bf(v0.w) << 16);
      pk.z = f2bf(v1.x) | ((unsigned)f2bf(v1.y) << 16);
      pk.w = f2bf(v1.z) | ((unsigned)f2bf(v1.w) << 16);
      *reinterpret_cast<uint4*>(&xs[row * 128 + ch]) = pk;
    }
  }
  __syncthreads();

  const int lane = tid & 63;
  const int wv = tid >> 6;
  const int wr = (wv >> 1) * 64;
  const int wc = (wv & 1) * 64;
  const int lr = lane & 31;
  const int lk = lane >> 5;

  f32x16 acc[2][2];
#pragma unroll
  for (int m = 0; m < 2; ++m)
#pragma unroll
    for (int j = 0; j < 2; ++j)
#pragma unroll
      for (int q = 0; q < 16; ++q) acc[m][j][q] = 0.f;

#pragma unroll
  for (int ks = 0; ks < 8; ++ks) {
    bf16x8 a[2], b[2];
#pragma unroll
    for (int m = 0; m < 2; ++m) {
      const int r = wr + m * 32 + lr;
      const int ch = ((ks * 2 + lk) ^ (r & 7)) << 3;
      a[m] = *reinterpret_cast<const bf16x8*>(&xs[r * 128 + ch]);
    }
#pragma unroll
    for (int j = 0; j < 2; ++j) {
      const int r = wc + j * 32 + lr;
      const int ch = ((ks * 2 + lk) ^ (r & 7)) << 3;
      b[j] = *reinterpret_cast<const bf16x8*>(&Ws[r * 128 + ch]);
    }
#pragma unroll
    for (int m = 0; m < 2; ++m)
#pragma unroll
      for (int j = 0; j < 2; ++j)
        acc[m][j] = __builtin_amdgcn_mfma_f32_32x32x16_bf16(a[m], b[j], acc[m][j], 0, 0, 0);
  }

#pragma unroll
  for (int m = 0; m < 2; ++m) {
#pragma unroll
    for (int reg = 0; reg < 16; ++reg) {
      const int rloc = (reg & 3) + 8 * (reg >> 2) + 4 * lk;
      const int r = row0 + wr + m * 32 + rloc;
      if (r < n) {
        const float dv = dinv[r];
#pragma unroll
        for (int j = 0; j < 2; ++j) {
          const int col = wc + j * 32 + lr;
          g[(size_t)r * D + col] = __float2bfloat16((acc[m][j][reg] + bias[col]) * dv);
        }
      }
    }
  }
}

// one wave per node: out[v] = dinv[v]*(g[v] + sum g[s]); bf16 g rows (256B/row).
// out stores are non-temporal (never re-read) to keep L2 for the g gather.
__global__ __launch_bounds__(256) void k_accum(
    const int* __restrict__ rowptr, const int* __restrict__ cnt,
    const int* __restrict__ srcs, const unsigned int* __restrict__ g2,
    const float* __restrict__ dinv, float2* __restrict__ out2, int n) {
  const int w = (int)(((size_t)blockIdx.x * 256 + threadIdx.x) >> 6);
  const int lane = threadIdx.x & 63;
  if (w >= n) return;
  const int beg = rowptr[w];
  const int num = cnt[w];
  const unsigned int v = g2[(size_t)w * 64 + lane];  // self-loop term
  float ax = __uint_as_float(v << 16);
  float ay = __uint_as_float(v & 0xffff0000u);
  int k = 0;
  for (; k + 8 <= num; k += 8) {
    unsigned int t[8];
#pragma unroll
    for (int u = 0; u < 8; ++u)
      t[u] = g2[(size_t)srcs[beg + k + u] * 64 + lane];
#pragma unroll
    for (int u = 0; u < 8; ++u) {
      ax += __uint_as_float(t[u] << 16);
      ay += __uint_as_float(t[u] & 0xffff0000u);
    }
  }
  for (; k < num; ++k) {
    const unsigned int t = g2[(size_t)srcs[beg + k] * 64 + lane];
    ax += __uint_as_float(t << 16);
    ay += __uint_as_float(t & 0xffff0000u);
  }
  const float dv = dinv[w];
  const float2 res = make_float2(ax * dv, ay * dv);
  __builtin_nontemporal_store(__builtin_bit_cast(double, res),
                              (double*)(out2 + (size_t)w * 64 + lane));
}

extern "C" void kernel_launch(void* const* d_in, const int* in_sizes, int n_in,
                              void* d_out, int out_size, void* d_ws, size_t ws_size,
                              hipStream_t stream) {
  const float* x = (const float*)d_in[0];
  const int* ei = (const int*)d_in[1];
  const float* W = (const float*)d_in[2];
  const float* b = (const float*)d_in[3];
  float* out = (float*)d_out;
  const int n = in_sizes[0] / D;
  const int e = in_sizes[1] / 2;
  const int* src = ei;      // edge_index[0]
  const int* dst = ei + e;  // edge_index[1]
  const int nc = (n + RN - 1) >> SHIFT;  // coarse buckets (98 for n=100k, <=128)

  char* ws = (char*)d_ws;
  const size_t nbb = ((size_t)n * 4 + 255) / 256 * 256;
  const size_t eb = ((size_t)e * 4 + 255) / 256 * 256;
  const size_t pb = ((size_t)nc << CAPLOG) * 4;  // pairs region (12.8 MB)
  int* cnt = (int*)ws;                             // n
  float* dinv = (float*)(ws + nbb);                // n
  int* rowptr = (int*)(ws + 2 * nbb);              // n
  int* bsums = (int*)(ws + 3 * nbb);               // <=512
  int* gcursor = (int*)(ws + 3 * nbb + 2048);      // <=128
  int* srcs = (int*)(ws + 3 * nbb + 4096);         // e
  unsigned* pairs = (unsigned*)(ws + 3 * nbb + 4096 + eb);  // nc*CAP uints
  __hip_bfloat16* g = (__hip_bfloat16*)(ws + 3 * nbb + 4096 + eb + pb);  // n*128

  const int nscan = (n + 1023) / 1024;

  hipMemsetAsync(cnt, 0, (size_t)n * 4, stream);
  k_initcur<<<1, 128, 0, stream>>>(gcursor, nc);
  k_psort<<<(e + 4095) / 4096, 256, 0, stream>>>(src, dst, cnt, gcursor, pairs, e, nc);
  k_scan1<<<nscan, 256, 0, stream>>>(cnt, rowptr, bsums, dinv, n);
  k_scan2<<<1, 256, 0, stream>>>(bsums, nscan);
  k_scan3<<<(n + 255) / 256, 256, 0, stream>>>(rowptr, bsums, n);
  k_gemm<<<(n + 127) / 128, 256, 0, stream>>>(x, W, b, dinv, g, n);
  k_fine<<<nc, 1024, 0, stream>>>(pairs, gcursor, rowptr, srcs, n);
  k_accum<<<(n + 3) / 4, 256, 0, stream>>>(rowptr, cnt, srcs, (const unsigned*)g,
                                           dinv, (float2*)out, n);
}

// Round 9
// 184.726 us; speedup vs baseline: 1.2328x; 1.2328x over previous
//
#include <hip/hip_runtime.h>
#include <hip/hip_bf16.h>
#include <cstddef>

#define D 128
#define SHIFT 9           // coarse bucket = 512 nodes
#define RN (1 << SHIFT)
#define CAPLOG 14         // per-bucket capacity 16384 (avg 8192; padded max ~12K)
#define CAP (1 << CAPLOG)

typedef __attribute__((ext_vector_type(8))) short bf16x8;
typedef __attribute__((ext_vector_type(16))) float f32x16;

static __device__ __forceinline__ unsigned short f2bf(float f) {
  return __builtin_bit_cast(unsigned short, __float2bfloat16(f));
}

__global__ void k_initcur(int* __restrict__ gcursor, int nc) {
  int c = blockIdx.x * blockDim.x + threadIdx.x;
  if (c < nc) gcursor[c] = c << CAPLOG;
}

// block-local counting sort into coarse buckets. Per-wave LDS hists (no global
// degree atomics). One gcursor atomic per (block,bucket) claims a contiguous
// run written by THIS block -> line-dense write-back.
// pairs packed 4B: src (22b) | local-dst (9b) << 22.
__global__ __launch_bounds__(256) void k_psort(
    const int* __restrict__ src, const int* __restrict__ dst,
    int* __restrict__ gcursor, unsigned* __restrict__ pairs, int e, int nc) {
  __shared__ int hist4[4][256];
  const int tid = threadIdx.x;
  const int w = tid >> 6;
  const int base = blockIdx.x * 4096;
  const int m = min(4096, e - base);
#pragma unroll
  for (int u = 0; u < 4; ++u) ((int*)hist4)[tid + 256 * u] = 0;
  __syncthreads();
  int myd[16], mys[16];
#pragma unroll
  for (int j = 0; j < 16; ++j) {
    const int i = tid + j * 256;
    if (i < m) {
      myd[j] = dst[base + i];
      mys[j] = src[base + i];
      atomicAdd(&hist4[w][myd[j] >> SHIFT], 1);
    }
  }
  __syncthreads();
  if (tid < nc) {
    const int t0 = hist4[0][tid], t1 = hist4[1][tid];
    const int t2 = hist4[2][tid], t3 = hist4[3][tid];
    const int tot = t0 + t1 + t2 + t3;
    int b = (tot > 0) ? atomicAdd(&gcursor[tid], tot) : 0;
    hist4[0][tid] = b;           // in-place per-wave cursors
    hist4[1][tid] = b + t0;
    hist4[2][tid] = b + t0 + t1;
    hist4[3][tid] = b + t0 + t1 + t2;
  }
  __syncthreads();
#pragma unroll
  for (int j = 0; j < 16; ++j) {
    const int i = tid + j * 256;
    if (i < m) {
      const int c = myd[j] >> SHIFT;
      const int pos = atomicAdd(&hist4[w][c], 1);
      const unsigned pk = (unsigned)mys[j] | ((unsigned)(myd[j] & (RN - 1)) << 22);
      __builtin_nontemporal_store(pk, &pairs[pos]);
    }
  }
}

// one block per bucket: LDS histogram -> degrees (dinv, cnt), local scan ->
// rowptr (padded to x8), then scatter srcs + pad with dummy src=n (zero g row).
__global__ __launch_bounds__(512) void k_fine(
    const unsigned* __restrict__ pairs, const int* __restrict__ gcursor,
    int* __restrict__ rowptr, int* __restrict__ cnt, float* __restrict__ dinv,
    int* __restrict__ srcs, int n) {
  __shared__ int hist[RN];    // count -> then global cursor
  __shared__ int rowL[RN];    // node's srcs base (global index)
  __shared__ int sdata[RN];   // inclusive scan of padded counts
  const int c = blockIdx.x;
  const int tid = threadIdx.x;
  const int node0 = c << SHIFT;
  const int nodes = min(RN, n - node0);
  hist[tid] = 0;
  __syncthreads();
  const int beg = c << CAPLOG;
  const int end = gcursor[c];
  for (int i = beg + tid; i < end; i += RN)
    atomicAdd(&hist[pairs[i] >> 22], 1);
  __syncthreads();
  const int deg = hist[tid];
  const int p = (deg + 7) & ~7;  // pad to x8 -> accum has no tail loop
  sdata[tid] = p;
  __syncthreads();
  for (int off = 1; off < RN; off <<= 1) {
    int t = (tid >= off) ? sdata[tid - off] : 0;
    __syncthreads();
    sdata[tid] += t;
    __syncthreads();
  }
  const int rbase = beg + sdata[tid] - p;  // exclusive scan
  rowL[tid] = rbase;
  hist[tid] = rbase;  // reuse as global write cursor
  if (tid < nodes) {
    rowptr[node0 + tid] = rbase;
    cnt[node0 + tid] = p;
    dinv[node0 + tid] = fminf(rsqrtf((float)(deg + 1)), 1.0e6f);
  }
  __syncthreads();
  for (int i = beg + tid; i < end; i += RN) {
    const unsigned pr = pairs[i];
    const int pos = atomicAdd(&hist[pr >> 22], 1);
    srcs[pos] = (int)(pr & 0x3FFFFFu);
  }
  __syncthreads();
  const int fend = rowL[tid] + p;
  for (int i = hist[tid]; i < fend; ++i) srcs[i] = n;  // dummy -> zero row
}

// g(bf16) = (x @ W^T + b) * dinv[r] via mfma_f32_32x32x16_bf16
__global__ __launch_bounds__(256) void k_gemm(
    const float* __restrict__ x, const float* __restrict__ W,
    const float* __restrict__ bias, const float* __restrict__ dinv,
    __hip_bfloat16* __restrict__ g, int n) {
  __shared__ unsigned short xs[128 * 128];
  __shared__ unsigned short Ws[128 * 128];
  const int tid = threadIdx.x;
  const int row0 = blockIdx.x * 128;

#pragma unroll
  for (int u = 0; u < 8; ++u) {
    const int f = tid + 256 * u;
    const int row = f >> 4;
    const int c = f & 15;
    const int ch = (c ^ (row & 7)) << 3;
    {
      const float4* p = reinterpret_cast<const float4*>(&W[(size_t)row * D + c * 8]);
      const float4 v0 = p[0], v1 = p[1];
      uint4 pk;
      pk.x = f2bf(v0.x) | ((unsigned)f2bf(v0.y) << 16);
      pk.y = f2bf(v0.z) | ((unsigned)f2bf(v0.w) << 16);
      pk.z = f2bf(v1.x) | ((unsigned)f2bf(v1.y) << 16);
      pk.w = f2bf(v1.z) | ((unsigned)f2bf(v1.w) << 16);
      *reinterpret_cast<uint4*>(&Ws[row * 128 + ch]) = pk;
    }
    {
      float4 v0 = make_float4(0.f, 0.f, 0.f, 0.f), v1 = v0;
      if (row0 + row < n) {
        const float4* p =
            reinterpret_cast<const float4*>(&x[(size_t)(row0 + row) * D + c * 8]);
        v0 = p[0]; v1 = p[1];
      }
      uint4 pk;
      pk.x = f2bf(v0.x) | ((unsigned)f2bf(v0.y) << 16);
      pk.y = f2bf(v0.z) | ((unsigned)f2bf(v0.w) << 16);
      pk.z = f2bf(v1.x) | ((unsigned)f2bf(v1.y) << 16);
      pk.w = f2bf(v1.z) | ((unsigned)f2bf(v1.w) << 16);
      *reinterpret_cast<uint4*>(&xs[row * 128 + ch]) = pk;
    }
  }
  __syncthreads();

  const int lane = tid & 63;
  const int wv = tid >> 6;
  const int wr = (wv >> 1) * 64;
  const int wc = (wv & 1) * 64;
  const int lr = lane & 31;
  const int lk = lane >> 5;

  f32x16 acc[2][2];
#pragma unroll
  for (int m = 0; m < 2; ++m)
#pragma unroll
    for (int j = 0; j < 2; ++j)
#pragma unroll
      for (int q = 0; q < 16; ++q) acc[m][j][q] = 0.f;

#pragma unroll
  for (int ks = 0; ks < 8; ++ks) {
    bf16x8 a[2], b[2];
#pragma unroll
    for (int m = 0; m < 2; ++m) {
      const int r = wr + m * 32 + lr;
      const int ch = ((ks * 2 + lk) ^ (r & 7)) << 3;
      a[m] = *reinterpret_cast<const bf16x8*>(&xs[r * 128 + ch]);
    }
#pragma unroll
    for (int j = 0; j < 2; ++j) {
      const int r = wc + j * 32 + lr;
      const int ch = ((ks * 2 + lk) ^ (r & 7)) << 3;
      b[j] = *reinterpret_cast<const bf16x8*>(&Ws[r * 128 + ch]);
    }
#pragma unroll
    for (int m = 0; m < 2; ++m)
#pragma unroll
      for (int j = 0; j < 2; ++j)
        acc[m][j] = __builtin_amdgcn_mfma_f32_32x32x16_bf16(a[m], b[j], acc[m][j], 0, 0, 0);
  }

#pragma unroll
  for (int m = 0; m < 2; ++m) {
#pragma unroll
    for (int reg = 0; reg < 16; ++reg) {
      const int rloc = (reg & 3) + 8 * (reg >> 2) + 4 * lk;
      const int r = row0 + wr + m * 32 + rloc;
      if (r < n) {
        const float dv = dinv[r];
#pragma unroll
        for (int j = 0; j < 2; ++j) {
          const int col = wc + j * 32 + lr;
          g[(size_t)r * D + col] = __float2bfloat16((acc[m][j][reg] + bias[col]) * dv);
        }
      }
    }
  }
}

// one wave per node: out[v] = dinv[v]*(g[v] + sum g[s]); num is a multiple of
// 8 (padded with zero-row dummies) -> pure unrolled loop, no tail.
__global__ __launch_bounds__(256) void k_accum(
    const int* __restrict__ rowptr, const int* __restrict__ cnt,
    const int* __restrict__ srcs, const unsigned int* __restrict__ g2,
    const float* __restrict__ dinv, float2* __restrict__ out2, int n) {
  const int w = (int)(((size_t)blockIdx.x * 256 + threadIdx.x) >> 6);
  const int lane = threadIdx.x & 63;
  if (w >= n) return;
  const int beg = rowptr[w];
  const int num = cnt[w];
  const unsigned int v = g2[(size_t)w * 64 + lane];  // self-loop term
  float ax = __uint_as_float(v << 16);
  float ay = __uint_as_float(v & 0xffff0000u);
  for (int k = 0; k < num; k += 8) {
    int s[8];
    unsigned int t[8];
#pragma unroll
    for (int u = 0; u < 8; ++u)
      s[u] = __builtin_nontemporal_load(&srcs[beg + k + u]);
#pragma unroll
    for (int u = 0; u < 8; ++u)
      t[u] = g2[(size_t)s[u] * 64 + lane];
#pragma unroll
    for (int u = 0; u < 8; ++u) {
      ax += __uint_as_float(t[u] << 16);
      ay += __uint_as_float(t[u] & 0xffff0000u);
    }
  }
  const float dv = dinv[w];
  const float2 res = make_float2(ax * dv, ay * dv);
  __builtin_nontemporal_store(__builtin_bit_cast(double, res),
                              (double*)(out2 + (size_t)w * 64 + lane));
}

extern "C" void kernel_launch(void* const* d_in, const int* in_sizes, int n_in,
                              void* d_out, int out_size, void* d_ws, size_t ws_size,
                              hipStream_t stream) {
  const float* x = (const float*)d_in[0];
  const int* ei = (const int*)d_in[1];
  const float* W = (const float*)d_in[2];
  const float* b = (const float*)d_in[3];
  float* out = (float*)d_out;
  const int n = in_sizes[0] / D;
  const int e = in_sizes[1] / 2;
  const int* src = ei;      // edge_index[0]
  const int* dst = ei + e;  // edge_index[1]
  const int nc = (n + RN - 1) >> SHIFT;  // coarse buckets (196 for n=100k, <=256)

  char* ws = (char*)d_ws;
  const size_t nbb = ((size_t)n * 4 + 255) / 256 * 256;
  const size_t pb = (((size_t)nc << CAPLOG) * 4 + 255) / 256 * 256;
  float* dinv = (float*)ws;                       // n
  int* rowptr = (int*)(ws + nbb);                 // n
  int* cnt = (int*)(ws + 2 * nbb);                // n (padded degree)
  int* gcursor = (int*)(ws + 3 * nbb);            // <=256
  int* srcs = (int*)(ws + 3 * nbb + 1024);        // nc*CAP ints
  char* pr_base = ws + 3 * nbb + 1024 + pb;
  unsigned* pairs = (unsigned*)pr_base;           // nc*CAP uints (dead after fine)
  // g aliases pairs (gemm runs after fine); (n+1) rows, row n = zeros
  __hip_bfloat16* g = (__hip_bfloat16*)pr_base;

  hipMemsetAsync(g + (size_t)n * D, 0, D * sizeof(__hip_bfloat16), stream);
  k_initcur<<<1, 256, 0, stream>>>(gcursor, nc);
  k_psort<<<(e + 4095) / 4096, 256, 0, stream>>>(src, dst, gcursor, pairs, e, nc);
  k_fine<<<nc, RN, 0, stream>>>(pairs, gcursor, rowptr, cnt, dinv, srcs, n);
  k_gemm<<<(n + 127) / 128, 256, 0, stream>>>(x, W, b, dinv, g, n);
  k_accum<<<(n + 3) / 4, 256, 0, stream>>>(rowptr, cnt, srcs, (const unsigned*)g,
                                           dinv, (float2*)out, n);
}

// Round 11
// 179.525 us; speedup vs baseline: 1.2686x; 1.0290x over previous
//
#include <hip/hip_runtime.h>
#include <hip/hip_bf16.h>
#include <cstddef>

#define D 128
#define SHIFT 9           // coarse bucket = 512 nodes
#define RN (1 << SHIFT)
#define CAPLOG 14         // per-bucket capacity 16384 (avg 8192; padded max ~12K)
#define CAP (1 << CAPLOG)

typedef __attribute__((ext_vector_type(8))) short bf16x8;
typedef __attribute__((ext_vector_type(16))) float f32x16;
typedef __attribute__((ext_vector_type(4))) float f32x4;

static __device__ __forceinline__ unsigned short f2bf(float f) {
  return __builtin_bit_cast(unsigned short, __float2bfloat16(f));
}
static __device__ __forceinline__ float bflo(unsigned u) {
  return __uint_as_float(u << 16);
}
static __device__ __forceinline__ float bfhi(unsigned u) {
  return __uint_as_float(u & 0xffff0000u);
}

// init gcursor and zero the dummy g row (row n)
__global__ void k_init(int* __restrict__ gcursor, int nc, unsigned* __restrict__ gz) {
  const int t = threadIdx.x;
  if (t < nc) gcursor[t] = t << CAPLOG;
  if (t < 64) gz[t] = 0;  // 128 bf16 = 64 uints
}

// block-local counting sort into coarse buckets. Per-wave LDS hists. One
// gcursor atomic per (block,bucket) claims a contiguous run written by THIS
// block -> line-dense write-back. pairs packed 4B: src(22b) | ldst(9b)<<22.
__global__ __launch_bounds__(256) void k_psort(
    const int* __restrict__ src, const int* __restrict__ dst,
    int* __restrict__ gcursor, unsigned* __restrict__ pairs, int e, int nc) {
  __shared__ int hist4[4][256];
  const int tid = threadIdx.x;
  const int w = tid >> 6;
  const int base = blockIdx.x * 4096;
  const int m = min(4096, e - base);
#pragma unroll
  for (int u = 0; u < 4; ++u) ((int*)hist4)[tid + 256 * u] = 0;
  __syncthreads();
  int myd[16], mys[16];
#pragma unroll
  for (int j = 0; j < 16; ++j) {
    const int i = tid + j * 256;
    if (i < m) {
      myd[j] = dst[base + i];
      mys[j] = src[base + i];
      atomicAdd(&hist4[w][myd[j] >> SHIFT], 1);
    }
  }
  __syncthreads();
  if (tid < nc) {
    const int t0 = hist4[0][tid], t1 = hist4[1][tid];
    const int t2 = hist4[2][tid], t3 = hist4[3][tid];
    const int tot = t0 + t1 + t2 + t3;
    int b = (tot > 0) ? atomicAdd(&gcursor[tid], tot) : 0;
    hist4[0][tid] = b;
    hist4[1][tid] = b + t0;
    hist4[2][tid] = b + t0 + t1;
    hist4[3][tid] = b + t0 + t1 + t2;
  }
  __syncthreads();
#pragma unroll
  for (int j = 0; j < 16; ++j) {
    const int i = tid + j * 256;
    if (i < m) {
      const int c = myd[j] >> SHIFT;
      const int pos = atomicAdd(&hist4[w][c], 1);
      const unsigned pk = (unsigned)mys[j] | ((unsigned)(myd[j] & (RN - 1)) << 22);
      __builtin_nontemporal_store(pk, &pairs[pos]);
    }
  }
}

// one block per bucket: LDS histogram -> degrees (dinv, cnt), local scan ->
// rowptr (padded to x8), then scatter srcs + pad with dummy src=n (zero g row).
__global__ __launch_bounds__(512) void k_fine(
    const unsigned* __restrict__ pairs, const int* __restrict__ gcursor,
    int* __restrict__ rowptr, int* __restrict__ cnt, float* __restrict__ dinv,
    int* __restrict__ srcs, int n) {
  __shared__ int hist[RN];
  __shared__ int rowL[RN];
  __shared__ int sdata[RN];
  const int c = blockIdx.x;
  const int tid = threadIdx.x;
  const int node0 = c << SHIFT;
  const int nodes = min(RN, n - node0);
  hist[tid] = 0;
  __syncthreads();
  const int beg = c << CAPLOG;
  const int end = gcursor[c];
  for (int i = beg + tid; i < end; i += RN)
    atomicAdd(&hist[pairs[i] >> 22], 1);
  __syncthreads();
  const int deg = hist[tid];
  const int p = (deg + 7) & ~7;  // pad to x8 -> accum has no tail loop
  sdata[tid] = p;
  __syncthreads();
  for (int off = 1; off < RN; off <<= 1) {
    int t = (tid >= off) ? sdata[tid - off] : 0;
    __syncthreads();
    sdata[tid] += t;
    __syncthreads();
  }
  const int rbase = beg + sdata[tid] - p;
  rowL[tid] = rbase;
  hist[tid] = rbase;
  if (tid < nodes) {
    rowptr[node0 + tid] = rbase;
    cnt[node0 + tid] = p;
    dinv[node0 + tid] = fminf(rsqrtf((float)(deg + 1)), 1.0e6f);
  }
  __syncthreads();
  for (int i = beg + tid; i < end; i += RN) {
    const unsigned pr = pairs[i];
    const int pos = atomicAdd(&hist[pr >> 22], 1);
    srcs[pos] = (int)(pr & 0x3FFFFFu);
  }
  __syncthreads();
  const int fend = rowL[tid] + p;
  for (int i = hist[tid]; i < fend; ++i) srcs[i] = n;  // dummy -> zero row
}

// g(bf16) = (x @ W^T + b) * dinv[r] via mfma_f32_32x32x16_bf16
__global__ __launch_bounds__(256) void k_gemm(
    const float* __restrict__ x, const float* __restrict__ W,
    const float* __restrict__ bias, const float* __restrict__ dinv,
    __hip_bfloat16* __restrict__ g, int n) {
  __shared__ unsigned short xs[128 * 128];
  __shared__ unsigned short Ws[128 * 128];
  const int tid = threadIdx.x;
  const int row0 = blockIdx.x * 128;

#pragma unroll
  for (int u = 0; u < 8; ++u) {
    const int f = tid + 256 * u;
    const int row = f >> 4;
    const int c = f & 15;
    const int ch = (c ^ (row & 7)) << 3;
    {
      const float4* p = reinterpret_cast<const float4*>(&W[(size_t)row * D + c * 8]);
      const float4 v0 = p[0], v1 = p[1];
      uint4 pk;
      pk.x = f2bf(v0.x) | ((unsigned)f2bf(v0.y) << 16);
      pk.y = f2bf(v0.z) | ((unsigned)f2bf(v0.w) << 16);
      pk.z = f2bf(v1.x) | ((unsigned)f2bf(v1.y) << 16);
      pk.w = f2bf(v1.z) | ((unsigned)f2bf(v1.w) << 16);
      *reinterpret_cast<uint4*>(&Ws[row * 128 + ch]) = pk;
    }
    {
      float4 v0 = make_float4(0.f, 0.f, 0.f, 0.f), v1 = v0;
      if (row0 + row < n) {
        const float4* p =
            reinterpret_cast<const float4*>(&x[(size_t)(row0 + row) * D + c * 8]);
        v0 = p[0]; v1 = p[1];
      }
      uint4 pk;
      pk.x = f2bf(v0.x) | ((unsigned)f2bf(v0.y) << 16);
      pk.y = f2bf(v0.z) | ((unsigned)f2bf(v0.w) << 16);
      pk.z = f2bf(v1.x) | ((unsigned)f2bf(v1.y) << 16);
      pk.w = f2bf(v1.z) | ((unsigned)f2bf(v1.w) << 16);
      *reinterpret_cast<uint4*>(&xs[row * 128 + ch]) = pk;
    }
  }
  __syncthreads();

  const int lane = tid & 63;
  const int wv = tid >> 6;
  const int wr = (wv >> 1) * 64;
  const int wc = (wv & 1) * 64;
  const int lr = lane & 31;
  const int lk = lane >> 5;

  f32x16 acc[2][2];
#pragma unroll
  for (int m = 0; m < 2; ++m)
#pragma unroll
    for (int j = 0; j < 2; ++j)
#pragma unroll
      for (int q = 0; q < 16; ++q) acc[m][j][q] = 0.f;

#pragma unroll
  for (int ks = 0; ks < 8; ++ks) {
    bf16x8 a[2], b[2];
#pragma unroll
    for (int m = 0; m < 2; ++m) {
      const int r = wr + m * 32 + lr;
      const int ch = ((ks * 2 + lk) ^ (r & 7)) << 3;
      a[m] = *reinterpret_cast<const bf16x8*>(&xs[r * 128 + ch]);
    }
#pragma unroll
    for (int j = 0; j < 2; ++j) {
      const int r = wc + j * 32 + lr;
      const int ch = ((ks * 2 + lk) ^ (r & 7)) << 3;
      b[j] = *reinterpret_cast<const bf16x8*>(&Ws[r * 128 + ch]);
    }
#pragma unroll
    for (int m = 0; m < 2; ++m)
#pragma unroll
      for (int j = 0; j < 2; ++j)
        acc[m][j] = __builtin_amdgcn_mfma_f32_32x32x16_bf16(a[m], b[j], acc[m][j], 0, 0, 0);
  }

#pragma unroll
  for (int m = 0; m < 2; ++m) {
#pragma unroll
    for (int reg = 0; reg < 16; ++reg) {
      const int rloc = (reg & 3) + 8 * (reg >> 2) + 4 * lk;
      const int r = row0 + wr + m * 32 + rloc;
      if (r < n) {
        const float dv = dinv[r];
#pragma unroll
        for (int j = 0; j < 2; ++j) {
          const int col = wc + j * 32 + lr;
          g[(size_t)r * D + col] = __float2bfloat16((acc[m][j][reg] + bias[col]) * dv);
        }
      }
    }
  }
}

// one wave per node; 2 edges/group-slot: half 0 (lanes 0-31) gathers even
// edges, half 1 odd edges, 8B/lane. srcs for the NEXT group prefetched during
// current gathers (one memory round-trip per iter, not two). Final cross-half
// combine via shfl_xor(32). num is a multiple of 8 (zero-row dummies).
__global__ __launch_bounds__(256) void k_accum(
    const int* __restrict__ rowptr, const int* __restrict__ cnt,
    const int* __restrict__ srcs, const uint2* __restrict__ gq,
    const float* __restrict__ dinv, float* __restrict__ out, int n) {
  const int w = (int)(((size_t)blockIdx.x * 256 + threadIdx.x) >> 6);
  const int lane = threadIdx.x & 63;
  if (w >= n) return;
  const int li = lane & 31;
  const int half = lane >> 5;
  const int beg = rowptr[w];
  const int num = cnt[w];

  // self term: half0 reads row w, half1 reads zero row n (dedup via xor-combine)
  const uint2 sv = gq[(size_t)(half ? n : w) * 32 + li];
  float a0 = bflo(sv.x), a1 = bfhi(sv.x), a2 = bflo(sv.y), a3 = bfhi(sv.y);

  if (num > 0) {
    const int2* s2 = (const int2*)(srcs + beg);
    int2 sp0 = s2[0], sp1 = s2[1], sp2 = s2[2], sp3 = s2[3];
    for (int k = 0; k < num; k += 8) {
      const int nxt = (k + 8 < num) ? (beg + k + 8) : beg;  // guarded prefetch
      const int2* s2n = (const int2*)(srcs + nxt);
      const int2 np0 = s2n[0], np1 = s2n[1], np2 = s2n[2], np3 = s2n[3];
      const int e0 = half ? sp0.y : sp0.x;
      const int e1 = half ? sp1.y : sp1.x;
      const int e2 = half ? sp2.y : sp2.x;
      const int e3 = half ? sp3.y : sp3.x;
      const uint2 t0 = gq[(size_t)e0 * 32 + li];
      const uint2 t1 = gq[(size_t)e1 * 32 + li];
      const uint2 t2 = gq[(size_t)e2 * 32 + li];
      const uint2 t3 = gq[(size_t)e3 * 32 + li];
      a0 += bflo(t0.x) + bflo(t1.x) + bflo(t2.x) + bflo(t3.x);
      a1 += bfhi(t0.x) + bfhi(t1.x) + bfhi(t2.x) + bfhi(t3.x);
      a2 += bflo(t0.y) + bflo(t1.y) + bflo(t2.y) + bflo(t3.y);
      a3 += bfhi(t0.y) + bfhi(t1.y) + bfhi(t2.y) + bfhi(t3.y);
      sp0 = np0; sp1 = np1; sp2 = np2; sp3 = np3;
    }
  }

  a0 += __shfl_xor(a0, 32);
  a1 += __shfl_xor(a1, 32);
  a2 += __shfl_xor(a2, 32);
  a3 += __shfl_xor(a3, 32);

  if (!half) {
    const float dv = dinv[w];
    f32x4 res;
    res[0] = a0 * dv; res[1] = a1 * dv; res[2] = a2 * dv; res[3] = a3 * dv;
    f32x4* dst = (f32x4*)(out + (size_t)w * D) + li;
    __builtin_nontemporal_store(res, dst);
  }
}

extern "C" void kernel_launch(void* const* d_in, const int* in_sizes, int n_in,
                              void* d_out, int out_size, void* d_ws, size_t ws_size,
                              hipStream_t stream) {
  const float* x = (const float*)d_in[0];
  const int* ei = (const int*)d_in[1];
  const float* W = (const float*)d_in[2];
  const float* b = (const float*)d_in[3];
  float* out = (float*)d_out;
  const int n = in_sizes[0] / D;
  const int e = in_sizes[1] / 2;
  const int* src = ei;      // edge_index[0]
  const int* dst = ei + e;  // edge_index[1]
  const int nc = (n + RN - 1) >> SHIFT;  // coarse buckets (196 for n=100k, <=256)

  char* ws = (char*)d_ws;
  const size_t nbb = ((size_t)n * 4 + 255) / 256 * 256;
  const size_t pb = (((size_t)nc << CAPLOG) * 4 + 255) / 256 * 256;
  float* dinv = (float*)ws;                       // n
  int* rowptr = (int*)(ws + nbb);                 // n
  int* cnt = (int*)(ws + 2 * nbb);                // n (padded degree)
  int* gcursor = (int*)(ws + 3 * nbb);            // <=256
  int* srcs = (int*)(ws + 3 * nbb + 1024);        // nc*CAP ints
  char* pr_base = ws + 3 * nbb + 1024 + pb;
  unsigned* pairs = (unsigned*)pr_base;           // nc*CAP uints (dead after fine)
  // g aliases pairs (gemm runs after fine); (n+1) rows, row n = zeros
  __hip_bfloat16* g = (__hip_bfloat16*)pr_base;

  k_init<<<1, 256, 0, stream>>>(gcursor, nc, (unsigned*)(g + (size_t)n * D));
  k_psort<<<(e + 4095) / 4096, 256, 0, stream>>>(src, dst, gcursor, pairs, e, nc);
  k_fine<<<nc, RN, 0, stream>>>(pairs, gcursor, rowptr, cnt, dinv, srcs, n);
  k_gemm<<<(n + 127) / 128, 256, 0, stream>>>(x, W, b, dinv, g, n);
  k_accum<<<(n + 3) / 4, 256, 0, stream>>>(rowptr, cnt, srcs, (const uint2*)g,
                                           dinv, out, n);
}

// Round 12
// 176.278 us; speedup vs baseline: 1.2919x; 1.0184x over previous
//
#include <hip/hip_runtime.h>
#include <hip/hip_bf16.h>
#include <cstddef>

#define D 128
#define SHIFT 9           // coarse bucket = 512 nodes
#define RN (1 << SHIFT)
#define CAPLOG 14         // per-bucket capacity 16384 (avg padded ~12288)
#define CAP (1 << CAPLOG)

typedef __attribute__((ext_vector_type(8))) short bf16x8;
typedef __attribute__((ext_vector_type(16))) float f32x16;
typedef __attribute__((ext_vector_type(4))) float f32x4;

static __device__ __forceinline__ unsigned short f2bf(float f) {
  return __builtin_bit_cast(unsigned short, __float2bfloat16(f));
}
static __device__ __forceinline__ float bflo(unsigned u) {
  return __uint_as_float(u << 16);
}
static __device__ __forceinline__ float bfhi(unsigned u) {
  return __uint_as_float(u & 0xffff0000u);
}

// init gcursor, zero dummy g row (row n), pre-convert W to bf16 (one-time)
__global__ void k_init(int* __restrict__ gcursor, int nc, unsigned* __restrict__ gz,
                       const float* __restrict__ W, unsigned short* __restrict__ Wbf) {
  const int t = blockIdx.x * 256 + threadIdx.x;
  if (t < nc) gcursor[t] = t << CAPLOG;
  if (t < 64) gz[t] = 0;  // 128 bf16 = 64 uints
  if (t < 128 * 128) Wbf[t] = f2bf(W[t]);
}

// block-local counting sort into coarse buckets. Per-wave LDS hists. One
// gcursor atomic per (block,bucket) claims a contiguous run written by THIS
// block -> line-dense write-back. pairs packed 4B: src(22b) | ldst(9b)<<22.
__global__ __launch_bounds__(256) void k_psort(
    const int* __restrict__ src, const int* __restrict__ dst,
    int* __restrict__ gcursor, unsigned* __restrict__ pairs, int e, int nc) {
  __shared__ int hist4[4][256];
  const int tid = threadIdx.x;
  const int w = tid >> 6;
  const int base = blockIdx.x * 4096;
  const int m = min(4096, e - base);
#pragma unroll
  for (int u = 0; u < 4; ++u) ((int*)hist4)[tid + 256 * u] = 0;
  __syncthreads();
  int myd[16], mys[16];
#pragma unroll
  for (int j = 0; j < 16; ++j) {
    const int i = tid + j * 256;
    if (i < m) {
      myd[j] = dst[base + i];
      mys[j] = src[base + i];
      atomicAdd(&hist4[w][myd[j] >> SHIFT], 1);
    }
  }
  __syncthreads();
  if (tid < nc) {
    const int t0 = hist4[0][tid], t1 = hist4[1][tid];
    const int t2 = hist4[2][tid], t3 = hist4[3][tid];
    const int tot = t0 + t1 + t2 + t3;
    int b = (tot > 0) ? atomicAdd(&gcursor[tid], tot) : 0;
    hist4[0][tid] = b;
    hist4[1][tid] = b + t0;
    hist4[2][tid] = b + t0 + t1;
    hist4[3][tid] = b + t0 + t1 + t2;
  }
  __syncthreads();
#pragma unroll
  for (int j = 0; j < 16; ++j) {
    const int i = tid + j * 256;
    if (i < m) {
      const int c = myd[j] >> SHIFT;
      const int pos = atomicAdd(&hist4[w][c], 1);
      const unsigned pk = (unsigned)mys[j] | ((unsigned)(myd[j] & (RN - 1)) << 22);
      __builtin_nontemporal_store(pk, &pairs[pos]);
    }
  }
}

// one block per bucket: LDS histogram -> degrees (dinv, cnt), local scan ->
// rowptr (padded to x16), then scatter srcs + pad with dummy src=n (zero row).
__global__ __launch_bounds__(512) void k_fine(
    const unsigned* __restrict__ pairs, const int* __restrict__ gcursor,
    int* __restrict__ rowptr, int* __restrict__ cnt, float* __restrict__ dinv,
    int* __restrict__ srcs, int n) {
  __shared__ int hist[RN];
  __shared__ int rowL[RN];
  __shared__ int sdata[RN];
  const int c = blockIdx.x;
  const int tid = threadIdx.x;
  const int node0 = c << SHIFT;
  const int nodes = min(RN, n - node0);
  hist[tid] = 0;
  __syncthreads();
  const int beg = c << CAPLOG;
  const int end = gcursor[c];
  for (int i = beg + tid; i < end; i += RN)
    atomicAdd(&hist[pairs[i] >> 22], 1);
  __syncthreads();
  const int deg = hist[tid];
  const int p = (deg + 15) & ~15;  // pad to x16 -> accum runs 16-edge groups
  sdata[tid] = p;
  __syncthreads();
  for (int off = 1; off < RN; off <<= 1) {
    int t = (tid >= off) ? sdata[tid - off] : 0;
    __syncthreads();
    sdata[tid] += t;
    __syncthreads();
  }
  const int rbase = beg + sdata[tid] - p;
  rowL[tid] = rbase;
  hist[tid] = rbase;
  if (tid < nodes) {
    rowptr[node0 + tid] = rbase;
    cnt[node0 + tid] = p;
    dinv[node0 + tid] = fminf(rsqrtf((float)(deg + 1)), 1.0e6f);
  }
  __syncthreads();
  for (int i = beg + tid; i < end; i += RN) {
    const unsigned pr = pairs[i];
    const int pos = atomicAdd(&hist[pr >> 22], 1);
    srcs[pos] = (int)(pr & 0x3FFFFFu);
  }
  __syncthreads();
  const int fend = rowL[tid] + p;
  for (int i = hist[tid]; i < fend; ++i) srcs[i] = n;  // dummy -> zero row
}

// g(bf16) = (x @ W^T + b) * dinv[r] via mfma_f32_32x32x16_bf16.
// Operand order: A=W-frag, B=x-frag -> lane holds one x-row, regs hold 4
// consecutive cols -> packed uint2 epilogue stores (16/thread, not 64 scalar).
__global__ __launch_bounds__(256) void k_gemm(
    const float* __restrict__ x, const unsigned short* __restrict__ Wbf,
    const float* __restrict__ bias, const float* __restrict__ dinv,
    __hip_bfloat16* __restrict__ g, int n) {
  __shared__ unsigned short xs[128 * 128];
  __shared__ unsigned short Ws[128 * 128];
  const int tid = threadIdx.x;
  const int row0 = blockIdx.x * 128;

#pragma unroll
  for (int u = 0; u < 8; ++u) {
    const int f = tid + 256 * u;
    const int row = f >> 4;
    const int c = f & 15;
    const int ch = (c ^ (row & 7)) << 3;
    // W tile: pre-converted bf16, straight uint4 copy
    *reinterpret_cast<uint4*>(&Ws[row * 128 + ch]) =
        *reinterpret_cast<const uint4*>(&Wbf[row * 128 + c * 8]);
    // x tile: f32 -> bf16 convert + pack
    float4 v0 = make_float4(0.f, 0.f, 0.f, 0.f), v1 = v0;
    if (row0 + row < n) {
      const float4* p =
          reinterpret_cast<const float4*>(&x[(size_t)(row0 + row) * D + c * 8]);
      v0 = p[0]; v1 = p[1];
    }
    uint4 pk;
    pk.x = f2bf(v0.x) | ((unsigned)f2bf(v0.y) << 16);
    pk.y = f2bf(v0.z) | ((unsigned)f2bf(v0.w) << 16);
    pk.z = f2bf(v1.x) | ((unsigned)f2bf(v1.y) << 16);
    pk.w = f2bf(v1.z) | ((unsigned)f2bf(v1.w) << 16);
    *reinterpret_cast<uint4*>(&xs[row * 128 + ch]) = pk;
  }
  __syncthreads();

  const int lane = tid & 63;
  const int wv = tid >> 6;
  const int xr0 = (wv >> 1) * 64;  // x-row tile offset
  const int cc0 = (wv & 1) * 64;   // col tile offset
  const int lr = lane & 31;
  const int lk = lane >> 5;

  f32x16 acc[2][2];  // [p: col subtile][q: row subtile]
#pragma unroll
  for (int p = 0; p < 2; ++p)
#pragma unroll
    for (int q = 0; q < 2; ++q)
#pragma unroll
      for (int t = 0; t < 16; ++t) acc[p][q][t] = 0.f;

#pragma unroll
  for (int ks = 0; ks < 8; ++ks) {
    bf16x8 a[2], b[2];
#pragma unroll
    for (int p = 0; p < 2; ++p) {
      const int r = cc0 + p * 32 + lr;  // W row (output col)
      const int ch = ((ks * 2 + lk) ^ (r & 7)) << 3;
      a[p] = *reinterpret_cast<const bf16x8*>(&Ws[r * 128 + ch]);
    }
#pragma unroll
    for (int q = 0; q < 2; ++q) {
      const int r = xr0 + q * 32 + lr;  // x row
      const int ch = ((ks * 2 + lk) ^ (r & 7)) << 3;
      b[q] = *reinterpret_cast<const bf16x8*>(&xs[r * 128 + ch]);
    }
#pragma unroll
    for (int p = 0; p < 2; ++p)
#pragma unroll
      for (int q = 0; q < 2; ++q)
        acc[p][q] = __builtin_amdgcn_mfma_f32_32x32x16_bf16(a[p], b[q], acc[p][q], 0, 0, 0);
  }

  // D layout: lane = x-row (q*32+lr), reg -> col (reg&3) + 8*(reg>>2) + 4*lk
#pragma unroll
  for (int q = 0; q < 2; ++q) {
    const int r = row0 + xr0 + q * 32 + lr;
    if (r < n) {
      const float dv = dinv[r];
#pragma unroll
      for (int p = 0; p < 2; ++p) {
#pragma unroll
        for (int rg = 0; rg < 4; ++rg) {
          const int cb = cc0 + p * 32 + 8 * rg + 4 * lk;
          const float v0 = (acc[p][q][rg * 4 + 0] + bias[cb + 0]) * dv;
          const float v1 = (acc[p][q][rg * 4 + 1] + bias[cb + 1]) * dv;
          const float v2 = (acc[p][q][rg * 4 + 2] + bias[cb + 2]) * dv;
          const float v3 = (acc[p][q][rg * 4 + 3] + bias[cb + 3]) * dv;
          uint2 pk;
          pk.x = f2bf(v0) | ((unsigned)f2bf(v1) << 16);
          pk.y = f2bf(v2) | ((unsigned)f2bf(v3) << 16);
          *reinterpret_cast<uint2*>(&g[(size_t)r * D + cb]) = pk;
        }
      }
    }
  }
}

// one wave per node; 16-edge groups: half 0 (lanes 0-31) gathers even edges,
// half 1 odd edges, 8B/lane -> 8 independent gathers in flight. srcs for the
// NEXT group prefetched (int4 x4) during current gathers. num % 16 == 0.
__global__ __launch_bounds__(256) void k_accum(
    const int* __restrict__ rowptr, const int* __restrict__ cnt,
    const int* __restrict__ srcs, const uint2* __restrict__ gq,
    const float* __restrict__ dinv, float* __restrict__ out, int n) {
  const int w = (int)(((size_t)blockIdx.x * 256 + threadIdx.x) >> 6);
  const int lane = threadIdx.x & 63;
  if (w >= n) return;
  const int li = lane & 31;
  const int half = lane >> 5;
  const int beg = rowptr[w];
  const int num = cnt[w];

  // self term: half0 reads row w, half1 reads zero row n
  const uint2 sv = gq[(size_t)(half ? n : w) * 32 + li];
  float a0 = bflo(sv.x), a1 = bfhi(sv.x), a2 = bflo(sv.y), a3 = bfhi(sv.y);

  if (num > 0) {
    const int4* s4 = (const int4*)(srcs + beg);
    int4 q0 = s4[0], q1 = s4[1], q2 = s4[2], q3 = s4[3];
    for (int k = 0; k < num; k += 16) {
      const int nx = (k + 16 < num) ? ((k + 16) >> 2) : 0;  // guarded prefetch
      const int4 n0 = s4[nx], n1 = s4[nx + 1], n2 = s4[nx + 2], n3 = s4[nx + 3];
      const int e0 = half ? q0.y : q0.x, e1 = half ? q0.w : q0.z;
      const int e2 = half ? q1.y : q1.x, e3 = half ? q1.w : q1.z;
      const int e4 = half ? q2.y : q2.x, e5 = half ? q2.w : q2.z;
      const int e6 = half ? q3.y : q3.x, e7 = half ? q3.w : q3.z;
      const uint2 t0 = gq[(size_t)e0 * 32 + li];
      const uint2 t1 = gq[(size_t)e1 * 32 + li];
      const uint2 t2 = gq[(size_t)e2 * 32 + li];
      const uint2 t3 = gq[(size_t)e3 * 32 + li];
      const uint2 t4 = gq[(size_t)e4 * 32 + li];
      const uint2 t5 = gq[(size_t)e5 * 32 + li];
      const uint2 t6 = gq[(size_t)e6 * 32 + li];
      const uint2 t7 = gq[(size_t)e7 * 32 + li];
      a0 += bflo(t0.x) + bflo(t1.x) + bflo(t2.x) + bflo(t3.x) +
            bflo(t4.x) + bflo(t5.x) + bflo(t6.x) + bflo(t7.x);
      a1 += bfhi(t0.x) + bfhi(t1.x) + bfhi(t2.x) + bfhi(t3.x) +
            bfhi(t4.x) + bfhi(t5.x) + bfhi(t6.x) + bfhi(t7.x);
      a2 += bflo(t0.y) + bflo(t1.y) + bflo(t2.y) + bflo(t3.y) +
            bflo(t4.y) + bflo(t5.y) + bflo(t6.y) + bflo(t7.y);
      a3 += bfhi(t0.y) + bfhi(t1.y) + bfhi(t2.y) + bfhi(t3.y) +
            bfhi(t4.y) + bfhi(t5.y) + bfhi(t6.y) + bfhi(t7.y);
      q0 = n0; q1 = n1; q2 = n2; q3 = n3;
    }
  }

  a0 += __shfl_xor(a0, 32);
  a1 += __shfl_xor(a1, 32);
  a2 += __shfl_xor(a2, 32);
  a3 += __shfl_xor(a3, 32);

  if (!half) {
    const float dv = dinv[w];
    f32x4 res;
    res[0] = a0 * dv; res[1] = a1 * dv; res[2] = a2 * dv; res[3] = a3 * dv;
    f32x4* dst = (f32x4*)(out + (size_t)w * D) + li;
    __builtin_nontemporal_store(res, dst);
  }
}

extern "C" void kernel_launch(void* const* d_in, const int* in_sizes, int n_in,
                              void* d_out, int out_size, void* d_ws, size_t ws_size,
                              hipStream_t stream) {
  const float* x = (const float*)d_in[0];
  const int* ei = (const int*)d_in[1];
  const float* W = (const float*)d_in[2];
  const float* b = (const float*)d_in[3];
  float* out = (float*)d_out;
  const int n = in_sizes[0] / D;
  const int e = in_sizes[1] / 2;
  const int* src = ei;      // edge_index[0]
  const int* dst = ei + e;  // edge_index[1]
  const int nc = (n + RN - 1) >> SHIFT;  // coarse buckets (196 for n=100k)

  char* ws = (char*)d_ws;
  const size_t nbb = ((size_t)n * 4 + 255) / 256 * 256;
  const size_t pb = (((size_t)nc << CAPLOG) * 4 + 255) / 256 * 256;
  float* dinv = (float*)ws;                         // n
  int* rowptr = (int*)(ws + nbb);                   // n
  int* cnt = (int*)(ws + 2 * nbb);                  // n (padded degree)
  int* gcursor = (int*)(ws + 3 * nbb);              // <=256 (1 KB)
  unsigned short* Wbf = (unsigned short*)(ws + 3 * nbb + 1024);  // 32 KB
  int* srcs = (int*)(ws + 3 * nbb + 1024 + 32768);  // nc*CAP ints
  char* pr_base = ws + 3 * nbb + 1024 + 32768 + pb;
  unsigned* pairs = (unsigned*)pr_base;             // nc*CAP uints (dead after fine)
  // g aliases pairs (gemm runs after fine); (n+1) rows, row n = zeros
  __hip_bfloat16* g = (__hip_bfloat16*)pr_base;

  k_init<<<64, 256, 0, stream>>>(gcursor, nc, (unsigned*)(g + (size_t)n * D), W, Wbf);
  k_psort<<<(e + 4095) / 4096, 256, 0, stream>>>(src, dst, gcursor, pairs, e, nc);
  k_fine<<<nc, RN, 0, stream>>>(pairs, gcursor, rowptr, cnt, dinv, srcs, n);
  k_gemm<<<(n + 127) / 128, 256, 0, stream>>>(x, Wbf, b, dinv, g, n);
  k_accum<<<(n + 3) / 4, 256, 0, stream>>>(rowptr, cnt, srcs, (const uint2*)g,
                                           dinv, out, n);
}